// Round 9
// baseline (412.615 us; speedup 1.0000x reference)
//
#include <hip/hip_runtime.h>
#include <hip/hip_bf16.h>
#include <math.h>

// Problem constants (B=2, S=2048, D=2048, H=16, hd=128)
#define BB 2
#define SS 2048
#define DD 2048
#define HH 16
#define HD 128
#define MM (BB * SS)                 // 4096 rows
#define SCALE 0.08838834764831845f  // 1/sqrt(128)

typedef __attribute__((ext_vector_type(8))) __bf16 bf16x8;
typedef __attribute__((ext_vector_type(4))) float f32x4;
typedef __attribute__((ext_vector_type(8))) unsigned short ushort8v;

__device__ __forceinline__ float bf2f(unsigned short u) {
    union { unsigned int u; float f; } x;
    x.u = ((unsigned int)u) << 16;
    return x.f;
}
__device__ __forceinline__ unsigned short f2bf(float f) {
    union { float f; unsigned int u; } x;
    x.f = f;
    unsigned int r = x.u + 0x7FFFu + ((x.u >> 16) & 1u);  // RNE (finite inputs)
    return (unsigned short)(r >> 16);
}

// ---------------------------------------------------------------------------
// Fused fp32 -> bf16 cast for x (8192 blocks) + Wq/Wk/Wv/Wo (4 x 4096 blocks).
// ---------------------------------------------------------------------------
__global__ __launch_bounds__(256) void cast_all(const float* __restrict__ x,
                                                const float* __restrict__ Wq,
                                                const float* __restrict__ Wk,
                                                const float* __restrict__ Wv,
                                                const float* __restrict__ Wo,
                                                unsigned short* __restrict__ xb,
                                                unsigned short* __restrict__ wqb) {
    int bid = blockIdx.x;
    const float* src;
    unsigned short* dst;
    int idx;
    if (bid < 8192) {
        src = x; dst = xb;
        idx = bid * 256 + threadIdx.x;
    } else {
        int seg = (bid - 8192) >> 12;             // 0..3
        idx = ((bid - 8192) & 4095) * 256 + threadIdx.x;
        src = (seg == 0) ? Wq : (seg == 1) ? Wk : (seg == 2) ? Wv : Wo;
        dst = wqb + (size_t)seg * ((size_t)DD * DD);
    }
    float4 v = ((const float4*)src)[idx];
    ushort4 o;
    o.x = f2bf(v.x); o.y = f2bf(v.y); o.z = f2bf(v.z); o.w = f2bf(v.w);
    ((ushort4*)dst)[idx] = o;
}

// ---------------------------------------------------------------------------
// RoPE cos/sin table (fp32): table[s][i], i<64.
// ---------------------------------------------------------------------------
__global__ __launch_bounds__(64) void rope_table_kernel(float* __restrict__ cost,
                                                        float* __restrict__ sint) {
    int s = blockIdx.x;
    int i = threadIdx.x;  // 0..63
    float inv = powf(10000.0f, -((float)(2 * i) / 128.0f));
    float ang = (float)s * inv;
    cost[s * 64 + i] = cosf(ang);
    sint[s * 64 + i] = sinf(ang);
}

// ---------------------------------------------------------------------------
// bf16 MFMA GEMM body (m97 structure), unchanged (803 TF measured).
// ---------------------------------------------------------------------------
#define GEMM_BODY(A_, W_, m0_, n0_, K_, ACC_)                                      \
    for (int k0 = 0; k0 < (K_); k0 += 32) {                                        \
        __syncthreads();                                                           \
        _Pragma("unroll")                                                          \
        for (int i = 0; i < 2; ++i) {                                              \
            int c = 2 * w + i;                                                     \
            int row = c * 16 + (l >> 2);                                           \
            const unsigned short* ga = (A_) + (size_t)((m0_) + row) * (K_) + k0 + (l & 3) * 8; \
            __builtin_amdgcn_global_load_lds(                                      \
                (const __attribute__((address_space(1))) unsigned int*)ga,         \
                (__attribute__((address_space(3))) unsigned int*)(As + c * 512),   \
                16, 0, 0);                                                         \
            const unsigned short* gb = (W_) + (size_t)((n0_) + row) * (K_) + k0 + (l & 3) * 8; \
            __builtin_amdgcn_global_load_lds(                                      \
                (const __attribute__((address_space(1))) unsigned int*)gb,         \
                (__attribute__((address_space(3))) unsigned int*)(Bs + c * 512),   \
                16, 0, 0);                                                         \
        }                                                                          \
        __syncthreads();                                                           \
        bf16x8 af[4], bfr[4];                                                      \
        _Pragma("unroll")                                                          \
        for (int i = 0; i < 4; ++i) {                                              \
            af[i]  = *(const bf16x8*)&As[(wr + i * 16 + rlane) * 32 + g * 8];      \
            bfr[i] = *(const bf16x8*)&Bs[(wc + i * 16 + rlane) * 32 + g * 8];      \
        }                                                                          \
        _Pragma("unroll")                                                          \
        for (int i = 0; i < 4; ++i)                                                \
            _Pragma("unroll")                                                      \
            for (int j = 0; j < 4; ++j)                                            \
                ACC_[i][j] = __builtin_amdgcn_mfma_f32_16x16x32_bf16(af[i], bfr[j], ACC_[i][j], 0, 0, 0); \
    }

__global__ __launch_bounds__(256) void gemm_qkv(const unsigned short* __restrict__ A,
                                                const unsigned short* __restrict__ Wc,
                                                unsigned short* __restrict__ qkv) {
    __shared__ unsigned short As[128 * 32];
    __shared__ unsigned short Bs[128 * 32];
    int t = threadIdx.x, w = t >> 6, l = t & 63;
    int rlane = l & 15, g = l >> 4;
    int flat = (int)blockIdx.y * 48 + (int)blockIdx.x;
    int swz = (flat & 7) * 192 + (flat >> 3);
    int n0 = (swz % 48) * 128;
    int m0 = (swz / 48) * 128;
    int wr = (w >> 1) * 64, wc = (w & 1) * 64;
    f32x4 acc[4][4] = {};
    GEMM_BODY(A, Wc, m0, n0, 2048, acc)
    unsigned short* base = qkv + (size_t)(n0 >> 11) * ((size_t)MM * DD);
    int nc0 = n0 & 2047;
#pragma unroll
    for (int i = 0; i < 4; ++i)
#pragma unroll
        for (int r = 0; r < 4; ++r) {
            int row = m0 + wr + i * 16 + g * 4 + r;
#pragma unroll
            for (int j = 0; j < 4; ++j) {
                int col = nc0 + wc + j * 16 + rlane;
                base[(size_t)row * DD + col] = f2bf(acc[i][j][r]);
            }
        }
}

__global__ __launch_bounds__(256) void gemm_out(const unsigned short* __restrict__ A,
                                                const unsigned short* __restrict__ W,
                                                float* __restrict__ C) {
    __shared__ unsigned short As[128 * 32];
    __shared__ unsigned short Bs[128 * 32];
    int t = threadIdx.x, w = t >> 6, l = t & 63;
    int rlane = l & 15, g = l >> 4;
    int flat = (int)blockIdx.y * 16 + (int)blockIdx.x;
    int swz = (flat & 7) * 64 + (flat >> 3);
    int n0 = (swz % 16) * 128;
    int m0 = (swz / 16) * 128;
    int wr = (w >> 1) * 64, wc = (w & 1) * 64;
    f32x4 acc[4][4] = {};
    GEMM_BODY(A, W, m0, n0, 2048, acc)
#pragma unroll
    for (int i = 0; i < 4; ++i)
#pragma unroll
        for (int r = 0; r < 4; ++r) {
            int row = m0 + wr + i * 16 + g * 4 + r;
#pragma unroll
            for (int j = 0; j < 4; ++j) {
                int col = n0 + wc + j * 16 + rlane;
                C[(size_t)row * DD + col] = acc[i][j][r];
            }
        }
}

// ---------------------------------------------------------------------------
// RoPE in-place on bf16 [rows, D] (q and k in one launch: rows = 2*MM).
// ---------------------------------------------------------------------------
__global__ __launch_bounds__(256) void rope_apply_kernel(unsigned short* __restrict__ arr,
                                                         const float* __restrict__ cost,
                                                         const float* __restrict__ sint) {
    int idx = blockIdx.x * 256 + threadIdx.x;
    int i4 = (idx & 15) * 4;
    int h = (idx >> 4) & 15;
    int row = idx >> 8;
    int s = row & (SS - 1);
    float4 c  = *(const float4*)&cost[s * 64 + i4];
    float4 sn = *(const float4*)&sint[s * 64 + i4];
    size_t p0 = (size_t)row * DD + h * HD + i4;
    ushort4 lo = *(ushort4*)&arr[p0];
    ushort4 hi = *(ushort4*)&arr[p0 + 64];
    ushort4 olo, ohi;
    olo.x = f2bf(bf2f(lo.x) * c.x - bf2f(hi.x) * sn.x);
    olo.y = f2bf(bf2f(lo.y) * c.y - bf2f(hi.y) * sn.y);
    olo.z = f2bf(bf2f(lo.z) * c.z - bf2f(hi.z) * sn.z);
    olo.w = f2bf(bf2f(lo.w) * c.w - bf2f(hi.w) * sn.w);
    ohi.x = f2bf(bf2f(hi.x) * c.x + bf2f(lo.x) * sn.x);
    ohi.y = f2bf(bf2f(hi.y) * c.y + bf2f(lo.y) * sn.y);
    ohi.z = f2bf(bf2f(hi.z) * c.z + bf2f(lo.z) * sn.z);
    ohi.w = f2bf(bf2f(hi.w) * c.w + bf2f(lo.w) * sn.w);
    *(ushort4*)&arr[p0] = olo;
    *(ushort4*)&arr[p0 + 64] = ohi;
}

// ---------------------------------------------------------------------------
// MFMA causal flash attention v5 — LDS-traffic-bound fix.
// Grid 512 (1D snake: gid<256 -> b=0, qt=15-m; else b=1, qt=m -> co-resident
// pairs sum to uniform 34 iters). 256 threads = 4 waves; block q-tile = 128,
// WAVE = 32 q rows (qg=2 x 16) -> 2x FLOP per LDS byte vs v4.
// K: dbuf LDS via global_load_lds, both-sides swizzle (read-conflict-free).
// Vt: single buffer, NEW slot swizzle slot=(d&7)^((d>>3)&7)^(k>>3) -> both
//     write phase (spread by vd8) and read phase (spread by l15&7) 2-way free.
// Ps: per-wave [32][72] (R3-verified layout). T13 defer-max; T5 setprio.
// LDS 66 KB -> 2 blocks/CU.
// ---------------------------------------------------------------------------
__global__ __launch_bounds__(256, 2) void mfma_attn(const unsigned short* __restrict__ qm,
                                                    const unsigned short* __restrict__ km,
                                                    const unsigned short* __restrict__ vm,
                                                    unsigned short* __restrict__ om) {
    __shared__ unsigned short Ks[2][64 * 128];   // 32 KB, swizzled layout
    __shared__ unsigned short Vt[128 * 64];      // 16 KB, slot-swizzled [d][k]
    __shared__ unsigned short Ps[4][32 * 72];    // 18 KB

    int t = threadIdx.x;
    int w = t >> 6;
    int l = t & 63;
    int l15 = l & 15;
    int g = l >> 4;

    int gid = blockIdx.x;
    int b = gid >> 8;                 // batch
    int h = (gid >> 4) & 15;          // head
    int m = gid & 15;
    int qt = b ? m : (15 - m);        // snake for co-resident load balance
    int q0 = qt * 128;
    size_t bbase = (size_t)b * SS * DD + (size_t)h * HD;

    int vk0 = 2 * (t >> 3);   // 0..62 even
    int vd8 = t & 7;
    int cbase = (l15 >> 2) & 3;
    int gsw = (g ^ (l15 & 3)) * 8;

    auto stage_k = [&](int kt2, int buf) {
#pragma unroll
        for (int s = 0; s < 4; ++s) {
            int row = w * 16 + s * 4 + (l >> 4);
            int c = ((l >> 2) & 3) ^ s;          // inverse swizzle on global src
            int gg = (l & 3) ^ (l >> 4);
            const unsigned short* ga = km + bbase +
                (size_t)(kt2 * 64 + row) * DD + c * 32 + gg * 8;
            __builtin_amdgcn_global_load_lds(
                (const __attribute__((address_space(1))) unsigned int*)ga,
                (__attribute__((address_space(3))) unsigned int*)(&Ks[buf][(w * 16 + s * 4) * 128]),
                16, 0, 0);
        }
    };

    ushort8v va[2], vb[2];
    auto load_v = [&](int kt2) {
        const unsigned short* vsrc = vm + bbase + (size_t)(kt2 * 64 + vk0) * DD + vd8 * 8;
        va[0] = *(const ushort8v*)(vsrc);
        vb[0] = *(const ushort8v*)(vsrc + DD);
        va[1] = *(const ushort8v*)(vsrc + 64);
        vb[1] = *(const ushort8v*)(vsrc + DD + 64);
    };
    auto write_v = [&]() {
#pragma unroll
        for (int i = 0; i < 2; ++i)
#pragma unroll
            for (int j = 0; j < 8; ++j) {
                int d = (vd8 + 8 * i) * 8 + j;
                int slot = j ^ vd8 ^ (vk0 >> 3);   // (d&7)^((d>>3)&7)^(k>>3)
                unsigned int pack = (unsigned int)va[i][j] | ((unsigned int)vb[i][j] << 16);
                *(unsigned int*)&Vt[d * 64 + slot * 8 + (vk0 & 7)] = pack;
            }
    };

    // Q fragments: wave w rows q0 + w*32 + qg*16 + l15, chunk c*32 + g*8
    bf16x8 qf[2][4];
#pragma unroll
    for (int qg = 0; qg < 2; ++qg) {
        int qrow = q0 + w * 32 + qg * 16 + l15;
#pragma unroll
        for (int c = 0; c < 4; ++c)
            qf[qg][c] = *(const bf16x8*)(qm + bbase + (size_t)qrow * DD + c * 32 + g * 8);
    }

    f32x4 acc_o[2][8] = {};
    float m_[2] = {-INFINITY, -INFINITY};
    float l_[2] = {0.0f, 0.0f};
    int nt = 2 * qt + 2;

    // prologue: tile 0
    stage_k(0, 0);
    load_v(0);
    write_v();
    __syncthreads();

    for (int kt = 0; kt < nt; ++kt) {
        int cur = kt & 1;
        bool pref = (kt + 1 < nt);
        if (pref) {
            stage_k(kt + 1, cur ^ 1);   // full-iteration DMA slack
            load_v(kt + 1);             // regs; written to Vt at iter end
        }

        // ---- S^T = K * Q^T : one K-frag read feeds BOTH qg (2x reuse) ----
        f32x4 s_[2][4] = {};
        __builtin_amdgcn_s_setprio(1);
#pragma unroll
        for (int c = 0; c < 4; ++c) {
            int coff = ((c ^ cbase) * 32) + gsw;
#pragma unroll
            for (int kg = 0; kg < 4; ++kg) {
                bf16x8 kf = *(const bf16x8*)&Ks[cur][(kg * 16 + l15) * 128 + coff];
#pragma unroll
                for (int qg = 0; qg < 2; ++qg)
                    s_[qg][kg] = __builtin_amdgcn_mfma_f32_16x16x32_bf16(
                        kf, qf[qg][c], s_[qg][kg], 0, 0, 0);
            }
        }
        __builtin_amdgcn_s_setprio(0);

        // ---- mask + online softmax per qg (T13 defer-max) ----
        float p[2][16];
        bool maskt = (kt >= 2 * qt);   // last two k-tiles touch the diagonal
#pragma unroll
        for (int qg = 0; qg < 2; ++qg) {
            int qglob = q0 + w * 32 + qg * 16 + l15;
#pragma unroll
            for (int kg = 0; kg < 4; ++kg)
#pragma unroll
                for (int r = 0; r < 4; ++r) {
                    float sv = s_[qg][kg][r] * SCALE;
                    if (maskt && (kt * 64 + kg * 16 + g * 4 + r > qglob)) sv = -INFINITY;
                    p[qg][kg * 4 + r] = sv;
                }
            float mt01 = fmaxf(fmaxf(p[qg][0], p[qg][1]), fmaxf(p[qg][2], p[qg][3]));
            float mt23 = fmaxf(fmaxf(p[qg][4], p[qg][5]), fmaxf(p[qg][6], p[qg][7]));
            float mt45 = fmaxf(fmaxf(p[qg][8], p[qg][9]), fmaxf(p[qg][10], p[qg][11]));
            float mt67 = fmaxf(fmaxf(p[qg][12], p[qg][13]), fmaxf(p[qg][14], p[qg][15]));
            float mt = fmaxf(fmaxf(mt01, mt23), fmaxf(mt45, mt67));
            mt = fmaxf(mt, __shfl_xor(mt, 16));
            mt = fmaxf(mt, __shfl_xor(mt, 32));
            if (!__all(mt - m_[qg] <= 8.0f)) {
                float mnew = fmaxf(m_[qg], mt);
                float alpha = __expf(m_[qg] - mnew);
                float ar[4];
#pragma unroll
                for (int r = 0; r < 4; ++r) ar[r] = __shfl(alpha, 4 * g + r);
#pragma unroll
                for (int dg = 0; dg < 8; ++dg)
#pragma unroll
                    for (int r = 0; r < 4; ++r) acc_o[qg][dg][r] *= ar[r];
                l_[qg] *= alpha;
                m_[qg] = mnew;
            }
            float ps = 0.0f;
#pragma unroll
            for (int n = 0; n < 16; ++n) {
                p[qg][n] = __expf(p[qg][n] - m_[qg]);
                ps += p[qg][n];
            }
            ps += __shfl_xor(ps, 16);
            ps += __shfl_xor(ps, 32);
            l_[qg] += ps;

            // P -> bf16 -> Ps (full 64-k row; same-wave in-order DS)
#pragma unroll
            for (int kg = 0; kg < 4; ++kg) {
                union { __bf16 hv[4]; uint2 u2; } pk;
#pragma unroll
                for (int r = 0; r < 4; ++r) pk.hv[r] = (__bf16)p[qg][kg * 4 + r];
                *(uint2*)&Ps[w][(qg * 16 + l15) * 72 + kg * 16 + g * 4] = pk.u2;
            }
        }

        // ---- PV: one Vt read feeds BOTH qg ----
        __builtin_amdgcn_s_setprio(1);
#pragma unroll
        for (int ks = 0; ks < 2; ++ks) {
            bf16x8 pf[2];
#pragma unroll
            for (int qg = 0; qg < 2; ++qg)
                pf[qg] = *(const bf16x8*)&Ps[w][(qg * 16 + l15) * 72 + ks * 32 + g * 8];
#pragma unroll
            for (int dg = 0; dg < 8; ++dg) {
                int d = dg * 16 + l15;
                int slot = (l15 & 7) ^ ((2 * dg + (l15 >> 3)) & 7) ^ (ks * 4 + g);
                bf16x8 vf = *(const bf16x8*)&Vt[d * 64 + slot * 8];
#pragma unroll
                for (int qg = 0; qg < 2; ++qg)
                    acc_o[qg][dg] = __builtin_amdgcn_mfma_f32_16x16x32_bf16(
                        pf[qg], vf, acc_o[qg][dg], 0, 0, 0);
            }
        }
        __builtin_amdgcn_s_setprio(0);

        __syncthreads();          // all waves done reading Vt/Ks[cur]
        if (pref) write_v();      // regs -> Vt for tile kt+1
        __syncthreads();          // Vt ready
    }

    // ---- epilogue: O / lsum -> bf16 ----
#pragma unroll
    for (int qg = 0; qg < 2; ++qg) {
        float lr[4];
#pragma unroll
        for (int r = 0; r < 4; ++r) lr[r] = 1.0f / __shfl(l_[qg], 4 * g + r);
#pragma unroll
        for (int dg = 0; dg < 8; ++dg)
#pragma unroll
            for (int r = 0; r < 4; ++r) {
                int qrow2 = q0 + w * 32 + qg * 16 + g * 4 + r;
                om[bbase + (size_t)qrow2 * DD + dg * 16 + l15] =
                    f2bf(acc_o[qg][dg][r] * lr[r]);
            }
    }
}

// ---------------------------------------------------------------------------
extern "C" void kernel_launch(void* const* d_in, const int* in_sizes, int n_in,
                              void* d_out, int out_size, void* d_ws, size_t ws_size,
                              hipStream_t stream) {
    const float* x  = (const float*)d_in[0];
    const float* Wq = (const float*)d_in[1];
    const float* Wk = (const float*)d_in[2];
    const float* Wv = (const float*)d_in[3];
    const float* Wo = (const float*)d_in[4];
    float* out = (float*)d_out;

    char* ws = (char*)d_ws;
    const size_t MD = (size_t)MM * DD;
    const size_t WN = (size_t)DD * DD;
    unsigned short* qb   = (unsigned short*)(ws);            // q,k,v contiguous
    unsigned short* kb   = (unsigned short*)(ws + 2 * MD);
    unsigned short* vb   = (unsigned short*)(ws + 4 * MD);
    unsigned short* ctxb = (unsigned short*)(ws + 6 * MD);
    unsigned short* xb   = (unsigned short*)(ws + 8 * MD);
    unsigned short* wqb  = (unsigned short*)(ws + 10 * MD);  // Wq,Wk,Wv,Wo contiguous
    unsigned short* wob  = (unsigned short*)(ws + 10 * MD + 6 * WN);
    float* cost = (float*)(ws + 10 * MD + 8 * WN);
    float* sint = cost + SS * 64;

    cast_all<<<8192 + 4 * 4096, 256, 0, stream>>>(x, Wq, Wk, Wv, Wo, xb, wqb);

    rope_table_kernel<<<SS, 64, 0, stream>>>(cost, sint);

    gemm_qkv<<<dim3(48, 32), 256, 0, stream>>>(xb, wqb, qb);

    rope_apply_kernel<<<2 * MM * HH * 16 / 256, 256, 0, stream>>>(qb, cost, sint);

    mfma_attn<<<512, 256, 0, stream>>>(qb, kb, vb, ctxb);

    gemm_out<<<dim3(16, 32), 256, 0, stream>>>(ctxb, wob, out);
}